// Round 2
// baseline (208.901 us; speedup 1.0000x reference)
//
#include <hip/hip_runtime.h>

// Problem constants
#define BATCH 8
#define SEQ   512
#define EMB   1024
#define NH    16
#define HD    64
// dist table rows = 2*512-1 = 1023 (+1 zero pad row)

typedef __bf16 bf16x8 __attribute__((ext_vector_type(8)));
typedef float  f32x4  __attribute__((ext_vector_type(4)));

__device__ __forceinline__ unsigned short f2bf(float f){
  union { float f; unsigned u; } v; v.f = f;
  unsigned r = v.u + 0x7FFFu + ((v.u >> 16) & 1u);
  return (unsigned short)(r >> 16);
}
__device__ __forceinline__ unsigned short f2bfr(float f){ // cheap round (values in [0,1])
  union { float f; unsigned u; } v; v.f = f;
  return (unsigned short)((v.u + 0x8000u) >> 16);
}

// XOR-swizzle helpers for LDS tiles with rows of 64 bf16 (128 B rows).
__device__ __forceinline__ int swzc(int row, int chunk){
  return row * 128 + (((chunk ^ (row & 7)) & 7) << 4);
}
__device__ __forceinline__ int swz2(int row, int col){ // col = bf16 element 0..63
  return row * 128 + ((((col >> 3) ^ (row & 7)) & 7) << 4) + ((col & 7) << 1);
}

// async global->LDS, 16B per lane, linear dest (wave-uniform base + lane*16)
__device__ __forceinline__ void gload16(const unsigned short* g, unsigned char* lds){
  __builtin_amdgcn_global_load_lds((const __attribute__((address_space(1))) unsigned int*)g,
                                   (__attribute__((address_space(3))) unsigned int*)lds,
                                   16, 0, 0);
}

// ---------------- prep kernels ----------------
__global__ void k_conv_hidden(const float* __restrict__ in, unsigned short* __restrict__ out){
  int i = (blockIdx.x * 256 + threadIdx.x) * 4;
  float4 v = *(const float4*)(in + i);
  ushort4 o; o.x = f2bf(v.x); o.y = f2bf(v.y); o.z = f2bf(v.z); o.w = f2bf(v.w);
  *(ushort4*)(out + i) = o;
}

__global__ void k_wt(const float* __restrict__ W, unsigned short* __restrict__ WT){
  __shared__ float t[32][33];
  int n0 = blockIdx.x * 32, k0 = blockIdx.y * 32;
  int tx = threadIdx.x, ty = threadIdx.y;
#pragma unroll
  for (int i = 0; i < 4; i++)
    t[ty + 8*i][tx] = W[(k0 + ty + 8*i) * EMB + n0 + tx];
  __syncthreads();
#pragma unroll
  for (int i = 0; i < 4; i++)
    WT[(n0 + ty + 8*i) * EMB + k0 + tx] = f2bf(t[tx][ty + 8*i]);
}

__global__ void k_dist(const float* __restrict__ in, unsigned short* __restrict__ out){
  int i = blockIdx.x * 256 + threadIdx.x;          // 1024*64 total
  out[i] = (i < 1023 * 64) ? f2bf(in[i]) : (unsigned short)0;
}

// ---------------- QKV projection GEMM ----------------
// C[m,n] = sum_k A[m,k] * W[k,n] + bias[n];  A bf16 [4096][1024], BT = W^T bf16 [1024][1024]
// mode 0: out[b,h,s,d] (Q,K)   mode 1: out[b,h,d,s] (V transposed)
__global__ __launch_bounds__(256) void k_gemm(const unsigned short* __restrict__ A,
                                              const unsigned short* __restrict__ BT,
                                              const float* __restrict__ bias,
                                              unsigned short* __restrict__ out, int mode){
  __shared__ __align__(16) unsigned char sA[128 * 128];
  __shared__ __align__(16) unsigned char sB[128 * 128];
  int m0 = blockIdx.y * 128, n0 = blockIdx.x * 128;
  int t = threadIdx.x, w = t >> 6, lane = t & 63, g = lane >> 4, lr = lane & 15;
  int rowbase = (w >> 1) * 64, colbase = (w & 1) * 64;
  int lrow = lane >> 3, lc = lane & 7;
  f32x4 acc[4][4] = {};
  for (int k0 = 0; k0 < EMB; k0 += 64){
    __syncthreads();
#pragma unroll
    for (int i = 0; i < 4; i++){
      int row = (w + 4*i) * 8 + lrow;            // 0..127, each exactly once
      int cg  = lc ^ (row & 7);                  // inverse-swizzled source chunk
      gload16(A  + (m0 + row) * EMB + k0 + cg*8, sA + (w + 4*i) * 1024);
      gload16(BT + (n0 + row) * EMB + k0 + cg*8, sB + (w + 4*i) * 1024);
    }
    __syncthreads();
#pragma unroll
    for (int kk = 0; kk < 2; kk++){
      bf16x8 af[4], bfv[4];
#pragma unroll
      for (int i = 0; i < 4; i++) af[i]  = *(const bf16x8*)(sA + swzc(rowbase + 16*i + lr, kk*4 + g));
#pragma unroll
      for (int j = 0; j < 4; j++) bfv[j] = *(const bf16x8*)(sB + swzc(colbase + 16*j + lr, kk*4 + g));
#pragma unroll
      for (int i = 0; i < 4; i++)
#pragma unroll
        for (int j = 0; j < 4; j++)
          acc[i][j] = __builtin_amdgcn_mfma_f32_16x16x32_bf16(af[i], bfv[j], acc[i][j], 0, 0, 0);
    }
  }
#pragma unroll
  for (int i = 0; i < 4; i++)
#pragma unroll
    for (int j = 0; j < 4; j++)
#pragma unroll
      for (int r = 0; r < 4; r++){
        int m = m0 + rowbase + 16*i + 4*g + r;
        int n = n0 + colbase + 16*j + lr;
        float val = acc[i][j][r] + bias[n];
        int b = m >> 9, s = m & 511, h = n >> 6, d = n & 63;
        int idx = (mode == 0) ? (((b*NH + h)*SEQ + s)*HD + d)
                              : (((b*NH + h)*HD + d)*SEQ + s);
        out[idx] = f2bf(val);
      }
}

// ---------------- fused rel-pos attention ----------------
// grid: 1024 = B*H*(S/64); block 256 = 4 waves x 16 l-rows each
// SA[l][r] = q_l . pe_{l-r}  (f32, stride 65 words)  -- rows partitioned per wave
// SB[r][l] = k_r . pe_{l-r}  (f32, stride 65 words)
__global__ __launch_bounds__(256) void k_attn(const unsigned short* __restrict__ qb,
                                              const unsigned short* __restrict__ kb,
                                              const unsigned short* __restrict__ vtb,
                                              const unsigned short* __restrict__ distb,
                                              const float* __restrict__ mask,
                                              float* __restrict__ out){
  __shared__ __align__(16) unsigned char sK[64 * 128];
  __shared__ __align__(16) unsigned char sV[64 * 128];   // V^T tile: [d][r]
  __shared__ __align__(16) unsigned char sSA[64 * 65 * 4];
  __shared__ __align__(16) unsigned char sSB[64 * 65 * 4];
  __shared__ float sMs[64];

  const float SCL = 0.125f * 1.4426950408889634f;   // /sqrt(64) * log2(e)

  int wg = blockIdx.x;
  int lt = wg & 7, h = (wg >> 3) & 15, b = wg >> 7;
  int L0 = lt * 64;
  int bh = b * NH + h;
  int t = threadIdx.x, w = t >> 6, lane = t & 63, g = lane >> 4, lr = lane & 15;
  int lbase = 16 * w;

  // Q fragments hoisted to registers (rows L0+16w+lr, shared by band-A and QK)
  const unsigned short* qrow = qb + (bh * SEQ + L0 + lbase + lr) * HD + 8 * g;
  bf16x8 aq0 = *(const bf16x8*)qrow;
  bf16x8 aq1 = *(const bf16x8*)(qrow + 32);

  f32x4 o[4] = {};
  float mrun[4], srun[4];
#pragma unroll
  for (int r = 0; r < 4; r++){ mrun[r] = -1e30f; srun[r] = 0.f; }

  for (int rt = 0; rt < 8; rt++){
    int R0 = rt * 64;
    int jb = L0 - R0 + 448;        // pe band start row (0..896)
    __syncthreads();
    { // stage K tile, V^T tile via global_load_lds (linear dest, inv-swizzled source)
      const unsigned short* ks = kb  + (bh * SEQ + R0) * HD;
      const unsigned short* vs = vtb + bh * HD * SEQ + R0;
#pragma unroll
      for (int i = 0; i < 2; i++){
        int row = (w + 4*i) * 8 + (lane >> 3);   // 0..63
        int cg  = (lane & 7) ^ (row & 7);
        gload16(ks + row * HD  + cg*8, sK + (w + 4*i) * 1024);
        gload16(vs + row * SEQ + cg*8, sV + (w + 4*i) * 1024);
      }
      if (t < 64) sMs[t] = mask[b * SEQ + R0 + t] * 1.4426950408889634f;
    }
    __syncthreads();

    { // band matmuls -> shifted f32 stores in score orientation
      const unsigned short* pbase = distb + (jb + lr) * HD + 8 * g;
      int rowb = lbase + 4 * g;
      // A band: valid jt in [w, w+4]
      for (int jt2 = 0; jt2 < 5; jt2++){
        int jt = w + jt2;
        const unsigned short* pr = pbase + jt * 16 * HD;
        bf16x8 pe0 = *(const bf16x8*)pr;
        bf16x8 pe1 = *(const bf16x8*)(pr + 32);
        f32x4 acc = {};
        acc = __builtin_amdgcn_mfma_f32_16x16x32_bf16(aq0, pe0, acc, 0, 0, 0);
        acc = __builtin_amdgcn_mfma_f32_16x16x32_bf16(aq1, pe1, acc, 0, 0, 0);
        int c0 = rowb + 63 - 16*jt - lr;           // rA for reg 0
        int a0 = rowb * 65 + c0;
#pragma unroll
        for (int r = 0; r < 4; r++)
          if ((unsigned)(c0 + r) < 64u) *(float*)(sSA + (a0 + 66*r) * 4) = acc[r];
      }
      // B band: valid jt in [3-w, 7-w]
      bf16x8 ak0 = *(const bf16x8*)(sK + swzc(lbase + lr, g));
      bf16x8 ak1 = *(const bf16x8*)(sK + swzc(lbase + lr, 4 + g));
      for (int jt2 = 0; jt2 < 5; jt2++){
        int jt = 3 - w + jt2;
        const unsigned short* pr = pbase + jt * 16 * HD;
        bf16x8 pe0 = *(const bf16x8*)pr;
        bf16x8 pe1 = *(const bf16x8*)(pr + 32);
        f32x4 acc = {};
        acc = __builtin_amdgcn_mfma_f32_16x16x32_bf16(ak0, pe0, acc, 0, 0, 0);
        acc = __builtin_amdgcn_mfma_f32_16x16x32_bf16(ak1, pe1, acc, 0, 0, 0);
        int c0 = 16*jt + lr + rowb - 63;           // l for reg 0
        int b0 = rowb * 65 + c0;
#pragma unroll
        for (int r = 0; r < 4; r++)
          if ((unsigned)(c0 + r) < 64u) *(float*)(sSB + (b0 + 66*r) * 4) = acc[r];
      }
    }
    __syncthreads();

    // QK^T scores + band adds + scale + mask (all in exp2 domain)
    f32x4 sc[4];
#pragma unroll
    for (int f = 0; f < 4; f++){
      bf16x8 bk0 = *(const bf16x8*)(sK + swzc(16*f + lr, g));
      bf16x8 bk1 = *(const bf16x8*)(sK + swzc(16*f + lr, 4 + g));
      f32x4 a = {};
      a = __builtin_amdgcn_mfma_f32_16x16x32_bf16(aq0, bk0, a, 0, 0, 0);
      a = __builtin_amdgcn_mfma_f32_16x16x32_bf16(aq1, bk1, a, 0, 0, 0);
#pragma unroll
      for (int r = 0; r < 4; r++){
        int lloc = lbase + 4*g + r;
        int rr = 16*f + lr;
        float add = *(const float*)(sSA + (lloc*65 + rr) * 4)
                  + *(const float*)(sSB + (rr*65 + lloc) * 4);
        a[r] = (a[r] + add) * SCL + sMs[rr];
      }
      sc[f] = a;
    }

    // online softmax (exp2 domain)
    float fac[4];
#pragma unroll
    for (int r = 0; r < 4; r++){
      float tm = fmaxf(fmaxf(sc[0][r], sc[1][r]), fmaxf(sc[2][r], sc[3][r]));
#pragma unroll
      for (int x = 1; x < 16; x <<= 1) tm = fmaxf(tm, __shfl_xor(tm, x, 16));
      float mnew = fmaxf(mrun[r], tm);
      float fr = exp2f(mrun[r] - mnew);
      float ps = 0.f;
#pragma unroll
      for (int f = 0; f < 4; f++){ float p = exp2f(sc[f][r] - mnew); sc[f][r] = p; ps += p; }
#pragma unroll
      for (int x = 1; x < 16; x <<= 1) ps += __shfl_xor(ps, x, 16);
      srun[r] = srun[r] * fr + ps;
      mrun[r] = mnew;
      fac[r]  = fr;
    }
#pragma unroll
    for (int df = 0; df < 4; df++)
#pragma unroll
      for (int r = 0; r < 4; r++) o[df][r] *= fac[r];

    // write P (bf16) into this wave's own SA stripe (dead after score; same-wave ordering)
    unsigned char* P = sSA + w * 4160;
#pragma unroll
    for (int f = 0; f < 4; f++)
#pragma unroll
      for (int r = 0; r < 4; r++)
        *(unsigned short*)(P + swz2(4*g + r, 16*f + lr)) = f2bfr(sc[f][r]);

    // PV: O[16 l x 64 d] += P[16 l x 64 r] * V[64 r x 64 d]
#pragma unroll
    for (int kk = 0; kk < 2; kk++){
      bf16x8 pf = *(const bf16x8*)(P + swzc(lr, kk*4 + g));
#pragma unroll
      for (int df = 0; df < 4; df++){
        bf16x8 vf = *(const bf16x8*)(sV + swzc(16*df + lr, kk*4 + g));
        o[df] = __builtin_amdgcn_mfma_f32_16x16x32_bf16(pf, vf, o[df], 0, 0, 0);
      }
    }
  }

  // epilogue: normalize and write out[b, l, h*64+d] (f32)
#pragma unroll
  for (int r = 0; r < 4; r++){
    float inv = 1.0f / srun[r];
#pragma unroll
    for (int df = 0; df < 4; df++){
      int l = L0 + lbase + 4*g + r;
      out[(b * SEQ + l) * EMB + h * HD + 16*df + lr] = o[df][r] * inv;
    }
  }
}

extern "C" void kernel_launch(void* const* d_in, const int* in_sizes, int n_in,
                              void* d_out, int out_size, void* d_ws, size_t ws_size,
                              hipStream_t stream) {
  (void)in_sizes; (void)n_in; (void)out_size; (void)ws_size;
  const float* hid  = (const float*)d_in[0];
  const float* mask = (const float*)d_in[1];
  const float* Wq   = (const float*)d_in[2];
  const float* bq   = (const float*)d_in[3];
  const float* Wk   = (const float*)d_in[4];
  const float* bk   = (const float*)d_in[5];
  const float* Wv   = (const float*)d_in[6];
  const float* bv   = (const float*)d_in[7];
  const float* dist = (const float*)d_in[8];
  float* out = (float*)d_out;

  unsigned char* ws = (unsigned char*)d_ws;
  unsigned short* hidb  = (unsigned short*)ws;                    // 4096*1024 bf16 = 8 MB
  unsigned short* wqt   = hidb + 4096 * 1024;                     // 2 MB each
  unsigned short* wkt   = wqt  + 1024 * 1024;
  unsigned short* wvt   = wkt  + 1024 * 1024;
  unsigned short* distb = wvt  + 1024 * 1024;                     // 1024*64 bf16 (padded)
  unsigned short* qb    = distb + 1024 * 64;                      // [B,H,S,D] bf16, 8 MB
  unsigned short* kb    = qb + BATCH * NH * SEQ * HD;
  unsigned short* vtb   = kb + BATCH * NH * SEQ * HD;             // [B,H,D,S] bf16

  k_conv_hidden<<<4096, 256, 0, stream>>>(hid, hidb);
  k_wt<<<dim3(32, 32), dim3(32, 8), 0, stream>>>(Wq, wqt);
  k_wt<<<dim3(32, 32), dim3(32, 8), 0, stream>>>(Wk, wkt);
  k_wt<<<dim3(32, 32), dim3(32, 8), 0, stream>>>(Wv, wvt);
  k_dist<<<256, 256, 0, stream>>>(dist, distb);

  k_gemm<<<dim3(8, 32), 256, 0, stream>>>(hidb, wqt, bq, qb, 0);
  k_gemm<<<dim3(8, 32), 256, 0, stream>>>(hidb, wkt, bk, kb, 0);
  k_gemm<<<dim3(8, 32), 256, 0, stream>>>(hidb, wvt, bv, vtb, 1);

  k_attn<<<1024, 256, 0, stream>>>(qb, kb, vtb, distb, mask, out);
}

// Round 3
// 164.738 us; speedup vs baseline: 1.2681x; 1.2681x over previous
//
#include <hip/hip_runtime.h>

// Problem constants
#define BATCH 8
#define SEQ   512
#define EMB   1024
#define NH    16
#define HD    64
// dist table rows = 2*512-1 = 1023 (+1 zero pad row)

typedef __bf16 bf16x8 __attribute__((ext_vector_type(8)));
typedef float  f32x4  __attribute__((ext_vector_type(4)));

__device__ __forceinline__ unsigned short f2bf(float f){
  union { float f; unsigned u; } v; v.f = f;
  unsigned r = v.u + 0x7FFFu + ((v.u >> 16) & 1u);
  return (unsigned short)(r >> 16);
}
__device__ __forceinline__ unsigned short f2bfr(float f){ // cheap round
  union { float f; unsigned u; } v; v.f = f;
  return (unsigned short)((v.u + 0x8000u) >> 16);
}
__device__ __forceinline__ float bf2f(unsigned short s){
  union { unsigned u; float f; } v; v.u = ((unsigned)s) << 16;
  return v.f;
}

// XOR-swizzle helpers for LDS tiles with rows of 64 bf16 (128 B rows).
__device__ __forceinline__ int swzc(int row, int chunk){
  return row * 128 + (((chunk ^ (row & 7)) & 7) << 4);
}
__device__ __forceinline__ int swz2(int row, int col){ // col = bf16 element 0..63
  return row * 128 + ((((col >> 3) ^ (row & 7)) & 7) << 4) + ((col & 7) << 1);
}

// async global->LDS, 16B per lane, linear dest (wave-uniform base + lane*16)
__device__ __forceinline__ void gload16(const unsigned short* g, unsigned char* lds){
  __builtin_amdgcn_global_load_lds((const __attribute__((address_space(1))) unsigned int*)g,
                                   (__attribute__((address_space(3))) unsigned int*)lds,
                                   16, 0, 0);
}

// ---------------- prep kernels ----------------
__global__ void k_conv_hidden(const float* __restrict__ in, unsigned short* __restrict__ out){
  int i = (blockIdx.x * 256 + threadIdx.x) * 4;
  float4 v = *(const float4*)(in + i);
  ushort4 o; o.x = f2bf(v.x); o.y = f2bf(v.y); o.z = f2bf(v.z); o.w = f2bf(v.w);
  *(ushort4*)(out + i) = o;
}

__global__ void k_wt(const float* __restrict__ W, unsigned short* __restrict__ WT){
  __shared__ float t[32][33];
  int n0 = blockIdx.x * 32, k0 = blockIdx.y * 32;
  int tx = threadIdx.x, ty = threadIdx.y;
#pragma unroll
  for (int i = 0; i < 4; i++)
    t[ty + 8*i][tx] = W[(k0 + ty + 8*i) * EMB + n0 + tx];
  __syncthreads();
#pragma unroll
  for (int i = 0; i < 4; i++)
    WT[(n0 + ty + 8*i) * EMB + k0 + tx] = f2bf(t[tx][ty + 8*i]);
}

__global__ void k_dist(const float* __restrict__ in, unsigned short* __restrict__ out){
  int i = blockIdx.x * 256 + threadIdx.x;          // 1024*64 total
  out[i] = (i < 1023 * 64) ? f2bf(in[i]) : (unsigned short)0;
}

// ---------------- QKV projection GEMM ----------------
__global__ __launch_bounds__(256) void k_gemm(const unsigned short* __restrict__ A,
                                              const unsigned short* __restrict__ BT,
                                              const float* __restrict__ bias,
                                              unsigned short* __restrict__ out, int mode){
  __shared__ __align__(16) unsigned char sA[128 * 128];
  __shared__ __align__(16) unsigned char sB[128 * 128];
  int m0 = blockIdx.y * 128, n0 = blockIdx.x * 128;
  int t = threadIdx.x, w = t >> 6, lane = t & 63, g = lane >> 4, lr = lane & 15;
  int rowbase = (w >> 1) * 64, colbase = (w & 1) * 64;
  int lrow = lane >> 3, lc = lane & 7;
  f32x4 acc[4][4] = {};
  for (int k0 = 0; k0 < EMB; k0 += 64){
    __syncthreads();
#pragma unroll
    for (int i = 0; i < 4; i++){
      int row = (w + 4*i) * 8 + lrow;
      int cg  = lc ^ (row & 7);
      gload16(A  + (m0 + row) * EMB + k0 + cg*8, sA + (w + 4*i) * 1024);
      gload16(BT + (n0 + row) * EMB + k0 + cg*8, sB + (w + 4*i) * 1024);
    }
    __syncthreads();
#pragma unroll
    for (int kk = 0; kk < 2; kk++){
      bf16x8 af[4], bfv[4];
#pragma unroll
      for (int i = 0; i < 4; i++) af[i]  = *(const bf16x8*)(sA + swzc(rowbase + 16*i + lr, kk*4 + g));
#pragma unroll
      for (int j = 0; j < 4; j++) bfv[j] = *(const bf16x8*)(sB + swzc(colbase + 16*j + lr, kk*4 + g));
#pragma unroll
      for (int i = 0; i < 4; i++)
#pragma unroll
        for (int j = 0; j < 4; j++)
          acc[i][j] = __builtin_amdgcn_mfma_f32_16x16x32_bf16(af[i], bfv[j], acc[i][j], 0, 0, 0);
    }
  }
#pragma unroll
  for (int i = 0; i < 4; i++)
#pragma unroll
    for (int j = 0; j < 4; j++)
#pragma unroll
      for (int r = 0; r < 4; r++){
        int m = m0 + rowbase + 16*i + 4*g + r;
        int n = n0 + colbase + 16*j + lr;
        float val = acc[i][j][r] + bias[n];
        int b = m >> 9, s = m & 511, h = n >> 6, d = n & 63;
        int idx = (mode == 0) ? (((b*NH + h)*SEQ + s)*HD + d)
                              : (((b*NH + h)*HD + d)*SEQ + s);
        out[idx] = f2bf(val);
      }
}

// ---------------- fused rel-pos attention ----------------
// grid: 1024 = B*H*(S/64); block 256 = 4 waves x 16 l-rows each.
// One barrier per r-tile. Per-wave private band stripes:
//   SA_T[r_kv][l_local]  (q_l . pe_{l-r}),  SB[r_kv][l_local]  (k_r . pe_{l-r})
// both bf16, 40 B row stride (bank-rotating), read back as ds_read_b64.
// PE fragments live in registers, prefetched one iteration ahead.
// K/V double-buffered via global_load_lds, prefetched at iteration top.
__global__ __launch_bounds__(256, 2) void k_attn(const unsigned short* __restrict__ qb,
                                                 const unsigned short* __restrict__ kb,
                                                 const unsigned short* __restrict__ vtb,
                                                 const unsigned short* __restrict__ distb,
                                                 const float* __restrict__ mask,
                                                 float* __restrict__ out){
  __shared__ __align__(16) unsigned char sK[2][64 * 128];
  __shared__ __align__(16) unsigned char sV[2][64 * 128];   // V^T tile: [d][r]
  __shared__ __align__(16) unsigned char sSA[4][2624];      // 65 rows x 40 B (row 64 = dump)
  __shared__ __align__(16) unsigned char sSB[4][2560];      // 64 rows x 40 B
  __shared__ __align__(16) unsigned char sP[4][2048];       // 16 rows x 128 B (swizzled)

  const float SCL  = 0.125f * 1.4426950408889634f;   // /sqrt(64) * log2(e)
  const float L2E  = 1.4426950408889634f;

  int wg = blockIdx.x;
  int lt = wg & 7, h = (wg >> 3) & 15, b = wg >> 7;
  int L0 = lt * 64;
  int bh = b * NH + h;
  int t = threadIdx.x, w = t >> 6, lane = t & 63, g = lane >> 4, lr = lane & 15;
  int lbase = 16 * w;
  unsigned char* mySA = sSA[w];
  unsigned char* mySB = sSB[w];
  unsigned char* myP  = sP[w];
  const float* maskp = mask + b * SEQ;

  // Q fragments hoisted to registers (rows L0+16w+lr)
  const unsigned short* qrow = qb + (bh * SEQ + L0 + lbase + lr) * HD + 8 * g;
  bf16x8 aq0 = *(const bf16x8*)qrow;
  bf16x8 aq1 = *(const bf16x8*)(qrow + 32);

  // PE fragments: 5 tiles jt = w..w+4, 2 k-halves each
  bf16x8 pe[5][2];
#define LOAD_PE(JB) do {                                                     \
    const unsigned short* _pb = distb + ((JB) + 16*w + lr) * HD + 8*g;       \
    _Pragma("unroll")                                                        \
    for (int _j = 0; _j < 5; _j++){                                          \
      pe[_j][0] = *(const bf16x8*)(_pb + _j*16*HD);                          \
      pe[_j][1] = *(const bf16x8*)(_pb + _j*16*HD + 32); }                   \
  } while(0)

  { // prologue: stage K/V for rt=0, load PE for rt=0
    const unsigned short* ks = kb  + bh * SEQ * HD;
    const unsigned short* vs = vtb + bh * HD * SEQ;
#pragma unroll
    for (int i = 0; i < 2; i++){
      int row = (w + 4*i) * 8 + (lane >> 3);
      int cg  = (lane & 7) ^ (row & 7);
      gload16(ks + row * HD  + cg*8, sK[0] + (w + 4*i) * 1024);
      gload16(vs + row * SEQ + cg*8, sV[0] + (w + 4*i) * 1024);
    }
    LOAD_PE(L0 + 448);
  }

  f32x4 o[4] = {};
  float mrun[4], srun[4];
#pragma unroll
  for (int r = 0; r < 4; r++){ mrun[r] = -1e30f; srun[r] = 0.f; }

  for (int rt = 0; rt < 8; rt++){
    int R0 = rt * 64;
    int cur = rt & 1;
    __syncthreads();   // drains this wave's outstanding gloads (vmcnt 0) + syncs

    // K/V prefetch for next iteration into alt buffers
    if (rt < 7){
      const unsigned short* ks = kb  + (bh * SEQ + R0 + 64) * HD;
      const unsigned short* vs = vtb + bh * HD * SEQ + R0 + 64;
#pragma unroll
      for (int i = 0; i < 2; i++){
        int row = (w + 4*i) * 8 + (lane >> 3);
        int cg  = (lane & 7) ^ (row & 7);
        gload16(ks + row * HD  + cg*8, sK[cur ^ 1] + (w + 4*i) * 1024);
        gload16(vs + row * SEQ + cg*8, sV[cur ^ 1] + (w + 4*i) * 1024);
      }
    }

    // mask values for this r-tile (column rr = 16f+lr)
    float mreg[4];
#pragma unroll
    for (int f = 0; f < 4; f++) mreg[f] = maskp[R0 + 16*f + lr];

    // merged QK + B-band per K-tile f (shares the two K fragment reads)
    f32x4 sc[4];
#pragma unroll
    for (int f = 0; f < 4; f++){
      bf16x8 k0 = *(const bf16x8*)(sK[cur] + swzc(16*f + lr, g));
      bf16x8 k1 = *(const bf16x8*)(sK[cur] + swzc(16*f + lr, 4 + g));
      f32x4 a = {};
      a = __builtin_amdgcn_mfma_f32_16x16x32_bf16(aq0, k0, a, 0, 0, 0);
      a = __builtin_amdgcn_mfma_f32_16x16x32_bf16(aq1, k1, a, 0, 0, 0);
      sc[f] = a;
      // B-band: i -> K rows 16f.., j -> PE tiles (3-f) and (4-f) relative to wave
      f32x4 b0 = {}, b1 = {};
      b0 = __builtin_amdgcn_mfma_f32_16x16x32_bf16(k0, pe[3 - f][0], b0, 0, 0, 0);
      b0 = __builtin_amdgcn_mfma_f32_16x16x32_bf16(k1, pe[3 - f][1], b0, 0, 0, 0);
      b1 = __builtin_amdgcn_mfma_f32_16x16x32_bf16(k0, pe[4 - f][0], b1, 0, 0, 0);
      b1 = __builtin_amdgcn_mfma_f32_16x16x32_bf16(k1, pe[4 - f][1], b1, 0, 0, 0);
#pragma unroll
      for (int reg = 0; reg < 4; reg++){
        int ss = 4*g + reg + lr;
        float v = (ss >= 15) ? b0[reg] : b1[reg];
        int row = 16*f + 4*g + reg;            // r_kv (block-local)
        int col = (ss + 1) & 15;               // l (wave-local) -- bijection
        *(unsigned short*)(mySB + row*40 + col*2) = f2bfr(v);
      }
    }

    // A-band: i -> q rows (wave-local l), j -> PE rows; store transposed [r_kv][l]
#pragma unroll
    for (int jt2 = 0; jt2 < 5; jt2++){
      f32x4 a = {};
      a = __builtin_amdgcn_mfma_f32_16x16x32_bf16(aq0, pe[jt2][0], a, 0, 0, 0);
      a = __builtin_amdgcn_mfma_f32_16x16x32_bf16(aq1, pe[jt2][1], a, 0, 0, 0);
#pragma unroll
      for (int reg = 0; reg < 4; reg++){
        int rloc = 63 + 4*g + reg - lr - 16*jt2;   // r_kv (block-local), may be OOR
        int addr = ((unsigned)rloc < 64u) ? (rloc*40 + (4*g + reg)*2) : 2560; // dump row
        *(unsigned short*)(mySA + addr) = f2bfr(a[reg]);
      }
    }

    // PE prefetch for next iteration (regs dead now; whole rest of iter to land)
    if (rt < 7) LOAD_PE(L0 + 448 - 64*(rt + 1));

    // score combine: qk + SA_T[rr][l] + SB[rr][l], scale, mask (exp2 domain)
#pragma unroll
    for (int f = 0; f < 4; f++){
      ushort4 sa = *(const ushort4*)(mySA + (16*f + lr)*40 + 8*g);
      ushort4 sb = *(const ushort4*)(mySB + (16*f + lr)*40 + 8*g);
      float madd = mreg[f] * L2E;
      sc[f][0] = (sc[f][0] + bf2f(sa.x) + bf2f(sb.x)) * SCL + madd;
      sc[f][1] = (sc[f][1] + bf2f(sa.y) + bf2f(sb.y)) * SCL + madd;
      sc[f][2] = (sc[f][2] + bf2f(sa.z) + bf2f(sb.z)) * SCL + madd;
      sc[f][3] = (sc[f][3] + bf2f(sa.w) + bf2f(sb.w)) * SCL + madd;
    }

    // online softmax (exp2 domain); rows = 4g+r, 16 lanes of group g hold 16 cols
    float fac[4];
#pragma unroll
    for (int r = 0; r < 4; r++){
      float tm = fmaxf(fmaxf(sc[0][r], sc[1][r]), fmaxf(sc[2][r], sc[3][r]));
#pragma unroll
      for (int x = 1; x < 16; x <<= 1) tm = fmaxf(tm, __shfl_xor(tm, x, 16));
      float mnew = fmaxf(mrun[r], tm);
      float fr = exp2f(mrun[r] - mnew);
      float ps = 0.f;
#pragma unroll
      for (int f = 0; f < 4; f++){ float p = exp2f(sc[f][r] - mnew); sc[f][r] = p; ps += p; }
#pragma unroll
      for (int x = 1; x < 16; x <<= 1) ps += __shfl_xor(ps, x, 16);
      srun[r] = srun[r] * fr + ps;
      mrun[r] = mnew;
      fac[r]  = fr;
    }
#pragma unroll
    for (int df = 0; df < 4; df++)
#pragma unroll
      for (int r = 0; r < 4; r++) o[df][r] *= fac[r];

    // write P (bf16) into this wave's private stripe
#pragma unroll
    for (int f = 0; f < 4; f++)
#pragma unroll
      for (int r = 0; r < 4; r++)
        *(unsigned short*)(myP + swz2(4*g + r, 16*f + lr)) = f2bfr(sc[f][r]);

    // PV: O[16 l x 64 d] += P[16 l x 64 r] * V[64 r x 64 d]
#pragma unroll
    for (int kk = 0; kk < 2; kk++){
      bf16x8 pf = *(const bf16x8*)(myP + swzc(lr, kk*4 + g));
#pragma unroll
      for (int df = 0; df < 4; df++){
        bf16x8 vf = *(const bf16x8*)(sV[cur] + swzc(16*df + lr, kk*4 + g));
        o[df] = __builtin_amdgcn_mfma_f32_16x16x32_bf16(pf, vf, o[df], 0, 0, 0);
      }
    }
  }

  // epilogue: normalize and write out[b, l, h*64+d] (f32)
#pragma unroll
  for (int r = 0; r < 4; r++){
    float inv = 1.0f / srun[r];
#pragma unroll
    for (int df = 0; df < 4; df++){
      int l = L0 + lbase + 4*g + r;
      out[(b * SEQ + l) * EMB + h * HD + 16*df + lr] = o[df][r] * inv;
    }
  }
#undef LOAD_PE
}

extern "C" void kernel_launch(void* const* d_in, const int* in_sizes, int n_in,
                              void* d_out, int out_size, void* d_ws, size_t ws_size,
                              hipStream_t stream) {
  (void)in_sizes; (void)n_in; (void)out_size; (void)ws_size;
  const float* hid  = (const float*)d_in[0];
  const float* mask = (const float*)d_in[1];
  const float* Wq   = (const float*)d_in[2];
  const float* bq   = (const float*)d_in[3];
  const float* Wk   = (const float*)d_in[4];
  const float* bk   = (const float*)d_in[5];
  const float* Wv   = (const float*)d_in[6];
  const float* bv   = (const float*)d_in[7];
  const float* dist = (const float*)d_in[8];
  float* out = (float*)d_out;

  unsigned char* ws = (unsigned char*)d_ws;
  unsigned short* hidb  = (unsigned short*)ws;                    // 4096*1024 bf16 = 8 MB
  unsigned short* wqt   = hidb + 4096 * 1024;                     // 2 MB each
  unsigned short* wkt   = wqt  + 1024 * 1024;
  unsigned short* wvt   = wkt  + 1024 * 1024;
  unsigned short* distb = wvt  + 1024 * 1024;                     // 1024*64 bf16 (padded)
  unsigned short* qb    = distb + 1024 * 64;                      // [B,H,S,D] bf16, 8 MB
  unsigned short* kb    = qb + BATCH * NH * SEQ * HD;
  unsigned short* vtb   = kb + BATCH * NH * SEQ * HD;             // [B,H,D,S] bf16

  k_conv_hidden<<<4096, 256, 0, stream>>>(hid, hidb);
  k_wt<<<dim3(32, 32), dim3(32, 8), 0, stream>>>(Wq, wqt);
  k_wt<<<dim3(32, 32), dim3(32, 8), 0, stream>>>(Wk, wkt);
  k_wt<<<dim3(32, 32), dim3(32, 8), 0, stream>>>(Wv, wvt);
  k_dist<<<256, 256, 0, stream>>>(dist, distb);

  k_gemm<<<dim3(8, 32), 256, 0, stream>>>(hidb, wqt, bq, qb, 0);
  k_gemm<<<dim3(8, 32), 256, 0, stream>>>(hidb, wkt, bk, kb, 0);
  k_gemm<<<dim3(8, 32), 256, 0, stream>>>(hidb, wvt, bv, vtb, 1);

  k_attn<<<1024, 256, 0, stream>>>(qb, kb, vtb, distb, mask, out);
}